// Round 7
// baseline (933.489 us; speedup 1.0000x reference)
//
#include <hip/hip_runtime.h>
#include <stdint.h>

#define PRIME_Y 2654435761u
#define PRIME_Z 805459861u
#define HASH_MASK 524287u   // 2^19 - 1
#define DENSE_TOTAL 315475u // entries in levels 0..2 (= OFFSETS[3])
#define HASHED_TOTAL (13u << 19)

typedef float f32x2 __attribute__((ext_vector_type(2)));
typedef float f32x4 __attribute__((ext_vector_type(4)));
typedef _Float16 h16x2 __attribute__((ext_vector_type(2)));
typedef _Float16 h16x4 __attribute__((ext_vector_type(4)));

__constant__ float c_scales[16] = {
    15.f, 31.f, 63.f, 127.f, 255.f, 511.f, 1023.f, 2047.f,
    4095.f, 8191.f, 16383.f, 32767.f, 65535.f, 131071.f, 262143.f, 524287.f};
__constant__ uint32_t c_offsets[16] = {
    0u, 4913u, 40850u, 315475u, 839763u, 1364051u, 1888339u, 2412627u,
    2936915u, 3461203u, 3985491u, 4509779u, 5034067u, 5558355u, 6082643u, 6606931u};
__constant__ uint32_t c_strides[3] = {17u, 33u, 65u};

// ---- Repack: fp32 emb -> fp16 tables. Hashed levels 3..15 at (l-3)<<19 (even,
// 8B-aligned bases for pair loads); dense levels 0..2 verbatim (first 315475). ----
__global__ __launch_bounds__(256) void repack_kernel(
    const float* __restrict__ emb, h16x2* __restrict__ tab, h16x2* __restrict__ dtab)
{
    const uint32_t t = blockIdx.x * 256 + threadIdx.x;
    const f32x2* __restrict__ e2 = reinterpret_cast<const f32x2*>(emb);
    if (t < HASHED_TOTAL) {
        const uint32_t lvl = t >> 19;            // 0..12 -> level lvl+3
        const uint32_t j = t & HASH_MASK;
        const f32x2 v = e2[c_offsets[lvl + 3] + j];
        h16x2 h; h.x = (_Float16)v.x; h.y = (_Float16)v.y;
        tab[t] = h;
    } else {
        const uint32_t j = t - HASHED_TOTAL;
        if (j < DENSE_TOTAL) {
            const f32x2 v = e2[j];
            h16x2 h; h.x = (_Float16)v.x; h.y = (_Float16)v.y;
            dtab[j] = h;
        }
    }
}

// ---- Pass 1: hashed levels 3..15, level-major; fp16 dump [chunk][13][256] ----
__global__ __launch_bounds__(256) void pass1_kernel(
    const float* __restrict__ in,     // [N,3]
    const h16x2* __restrict__ tab,    // repacked fp16 hashed tables
    h16x2* __restrict__ dump,         // [chunks][13][256]
    int N, int chunks)
{
    const int bid = blockIdx.x;
    const int lev_i = bid / chunks;                 // 0..12 -> level lev_i+3
    const int chunk = bid - lev_i * chunks;
    const int i = chunk * 256 + threadIdx.x;
    if (i >= N) return;
    const int level = lev_i + 3;

    // NT input loads: stream-once data, don't evict the level table from L2
    const float px = __builtin_nontemporal_load(&in[3 * i + 0]);
    const float py = __builtin_nontemporal_load(&in[3 * i + 1]);
    const float pz = __builtin_nontemporal_load(&in[3 * i + 2]);
    const float x = (px + 1.0f) * 0.5f;
    const float y = (py + 1.0f) * 0.5f;
    const float z = (pz + 1.0f) * 0.5f;

    const float scale = c_scales[level];

    const float posx = __fadd_rn(__fmul_rn(x, scale), 0.5f);
    const float posy = __fadd_rn(__fmul_rn(y, scale), 0.5f);
    const float posz = __fadd_rn(__fmul_rn(z, scale), 0.5f);

    const float gx = floorf(posx), gy = floorf(posy), gz = floorf(posz);
    const float fx = posx - gx, fy = posy - gy, fz = posz - gz;
    const uint32_t bx = (uint32_t)gx, by = (uint32_t)gy, bz = (uint32_t)gz;

    const float wx0 = 1.0f - fx, wx1 = fx;
    const float wy0 = 1.0f - fy, wy1 = fy;
    const float wz0 = 1.0f - fz, wz1 = fz;
    const float wxy00 = wx0 * wy0, wxy10 = wx1 * wy0;
    const float wxy01 = wx0 * wy1, wxy11 = wx1 * wy1;

    const uint32_t hy0 = by * PRIME_Y, hy1 = hy0 + PRIME_Y;
    const uint32_t hz0 = bz * PRIME_Z, hz1 = hz0 + PRIME_Z;

    uint32_t idx[8];
    idx[0] = (bx ^ hy0 ^ hz0) & HASH_MASK;
    idx[1] = ((bx + 1) ^ hy0 ^ hz0) & HASH_MASK;
    idx[2] = (bx ^ hy1 ^ hz0) & HASH_MASK;
    idx[3] = ((bx + 1) ^ hy1 ^ hz0) & HASH_MASK;
    idx[4] = (bx ^ hy0 ^ hz1) & HASH_MASK;
    idx[5] = ((bx + 1) ^ hy0 ^ hz1) & HASH_MASK;
    idx[6] = (bx ^ hy1 ^ hz1) & HASH_MASK;
    idx[7] = ((bx + 1) ^ hy1 ^ hz1) & HASH_MASK;

    const float w[8] = {
        wxy00 * wz0, wxy10 * wz0, wxy01 * wz0, wxy11 * wz0,
        wxy00 * wz1, wxy10 * wz1, wxy01 * wz1, wxy11 * wz1};

    const h16x2* __restrict__ tl = tab + ((size_t)lev_i << 19);
    const h16x4* __restrict__ tp = reinterpret_cast<const h16x4*>(tl);
    const bool oddx = (bx & 1u) != 0u;

    float f0 = 0.0f, f1 = 0.0f;
#pragma unroll
    for (int p = 0; p < 4; ++p) {
        const uint32_t i0 = idx[2 * p];
        const uint32_t i1 = idx[2 * p + 1];
        // one aligned 8B load covers entries {i0&~1, i0|1}
        const h16x4 q = tp[i0 >> 1];
        const bool hi = (i0 & 1u) != 0u;
        float c0x = (float)(hi ? q.z : q.x);
        float c0y = (float)(hi ? q.w : q.y);
        float c1x = (float)(hi ? q.x : q.z);
        float c1y = (float)(hi ? q.y : q.w);
        if (oddx) {  // exec-masked fallback: only odd-bx lanes issue this load
            const h16x2 tq = tl[i1];
            c1x = (float)tq.x;
            c1y = (float)tq.y;
        }
        f0 += w[2 * p] * c0x;     f1 += w[2 * p] * c0y;
        f0 += w[2 * p + 1] * c1x; f1 += w[2 * p + 1] * c1y;
    }

    h16x2 r; r.x = (_Float16)f0; r.y = (_Float16)f1;
    union { h16x2 h; uint32_t u; } cv; cv.h = r;
    uint32_t* dst = reinterpret_cast<uint32_t*>(&dump[((size_t)chunk * 13 + lev_i) * 256 + threadIdx.x]);
    __builtin_nontemporal_store(cv.u, dst);
}

// ---- Pass 2: dense levels 0..2 (fp16 table) + transpose dump -> out[N][32] ----
__global__ __launch_bounds__(256) void pass2_kernel(
    const float* __restrict__ in,
    const h16x2* __restrict__ dtab,  // fp16 dense tables, levels 0..2
    const h16x2* __restrict__ dump,  // [chunks][13][256]
    float* __restrict__ out, int N)
{
    const int c = blockIdx.x;
    const int t = threadIdx.x;
    const int i = c * 256 + t;
    if (i >= N) return;

    float acc[32];

    const float x = (in[3 * i + 0] + 1.0f) * 0.5f;
    const float y = (in[3 * i + 1] + 1.0f) * 0.5f;
    const float z = (in[3 * i + 2] + 1.0f) * 0.5f;

#pragma unroll
    for (int l = 0; l < 3; ++l) {
        const float scale = c_scales[l];
        const uint32_t off = c_offsets[l];
        const float posx = __fadd_rn(__fmul_rn(x, scale), 0.5f);
        const float posy = __fadd_rn(__fmul_rn(y, scale), 0.5f);
        const float posz = __fadd_rn(__fmul_rn(z, scale), 0.5f);
        const float gx = floorf(posx), gy = floorf(posy), gz = floorf(posz);
        const float fx = posx - gx, fy = posy - gy, fz = posz - gz;
        const uint32_t bx = (uint32_t)gx, by = (uint32_t)gy, bz = (uint32_t)gz;
        const float wx0 = 1.0f - fx, wx1 = fx;
        const float wy0 = 1.0f - fy, wy1 = fy;
        const float wz0 = 1.0f - fz, wz1 = fz;
        const float wxy00 = wx0 * wy0, wxy10 = wx1 * wy0;
        const float wxy01 = wx0 * wy1, wxy11 = wx1 * wy1;

        const uint32_t s = c_strides[l];
        const uint32_t s2 = s * s;
        const uint32_t r0 = by * s + bz * s2;
        const uint32_t r1 = r0 + s;
        const uint32_t r2 = r0 + s2;
        const uint32_t r3 = r1 + s2;
        uint32_t idx[8];
        idx[0] = bx + r0; idx[1] = bx + 1 + r0;
        idx[2] = bx + r1; idx[3] = bx + 1 + r1;
        idx[4] = bx + r2; idx[5] = bx + 1 + r2;
        idx[6] = bx + r3; idx[7] = bx + 1 + r3;

        const float w[8] = {
            wxy00 * wz0, wxy10 * wz0, wxy01 * wz0, wxy11 * wz0,
            wxy00 * wz1, wxy10 * wz1, wxy01 * wz1, wxy11 * wz1};

        float f0 = 0.0f, f1 = 0.0f;
#pragma unroll
        for (int cc = 0; cc < 8; ++cc) {
            const h16x2 q = dtab[idx[cc] + off];
            f0 += w[cc] * (float)q.x;
            f1 += w[cc] * (float)q.y;
        }

        acc[2 * l + 0] = f0;
        acc[2 * l + 1] = f1;
    }

#pragma unroll
    for (int li = 0; li < 13; ++li) {
        const h16x2 f = dump[((size_t)c * 13 + li) * 256 + t];
        acc[2 * (li + 3) + 0] = (float)f.x;
        acc[2 * (li + 3) + 1] = (float)f.y;
    }

    f32x4* __restrict__ o4 = reinterpret_cast<f32x4*>(out + (size_t)i * 32);
#pragma unroll
    for (int q = 0; q < 8; ++q) {
        f32x4 v;
        v.x = acc[4 * q + 0];
        v.y = acc[4 * q + 1];
        v.z = acc[4 * q + 2];
        v.w = acc[4 * q + 3];
        o4[q] = v;   // plain store — let L2 assemble full lines
    }
}

// ---- Fallback: fused single-pass fp32 (if ws too small) ----
__global__ __launch_bounds__(256) void hash_encode_fused_kernel(
    const float* __restrict__ in,
    const float* __restrict__ emb,
    float* __restrict__ out,
    int N)
{
    const int i = blockIdx.x * 256 + threadIdx.x;
    if (i >= N) return;

    const float x = (in[3 * i + 0] + 1.0f) * 0.5f;
    const float y = (in[3 * i + 1] + 1.0f) * 0.5f;
    const float z = (in[3 * i + 2] + 1.0f) * 0.5f;

    const f32x2* __restrict__ e2 = reinterpret_cast<const f32x2*>(emb);
    float acc[32];

#pragma unroll
    for (int l = 0; l < 16; ++l) {
        const float scale = c_scales[l];
        const uint32_t off = c_offsets[l];
        const float posx = __fadd_rn(__fmul_rn(x, scale), 0.5f);
        const float posy = __fadd_rn(__fmul_rn(y, scale), 0.5f);
        const float posz = __fadd_rn(__fmul_rn(z, scale), 0.5f);
        const float gx = floorf(posx), gy = floorf(posy), gz = floorf(posz);
        const float fx = posx - gx, fy = posy - gy, fz = posz - gz;
        const uint32_t bx = (uint32_t)gx, by = (uint32_t)gy, bz = (uint32_t)gz;
        const float wx0 = 1.0f - fx, wx1 = fx;
        const float wy0 = 1.0f - fy, wy1 = fy;
        const float wz0 = 1.0f - fz, wz1 = fz;
        const float wxy00 = wx0 * wy0, wxy10 = wx1 * wy0;
        const float wxy01 = wx0 * wy1, wxy11 = wx1 * wy1;

        uint32_t idx[8];
        if (l < 3) {
            const uint32_t s = c_strides[l];
            const uint32_t s2 = s * s;
            const uint32_t r0 = by * s + bz * s2;
            const uint32_t r1 = r0 + s;
            const uint32_t r2 = r0 + s2;
            const uint32_t r3 = r1 + s2;
            idx[0] = bx + r0; idx[1] = bx + 1 + r0;
            idx[2] = bx + r1; idx[3] = bx + 1 + r1;
            idx[4] = bx + r2; idx[5] = bx + 1 + r2;
            idx[6] = bx + r3; idx[7] = bx + 1 + r3;
        } else {
            const uint32_t hy0 = by * PRIME_Y, hy1 = hy0 + PRIME_Y;
            const uint32_t hz0 = bz * PRIME_Z, hz1 = hz0 + PRIME_Z;
            idx[0] = (bx ^ hy0 ^ hz0) & HASH_MASK;
            idx[1] = ((bx + 1) ^ hy0 ^ hz0) & HASH_MASK;
            idx[2] = (bx ^ hy1 ^ hz0) & HASH_MASK;
            idx[3] = ((bx + 1) ^ hy1 ^ hz0) & HASH_MASK;
            idx[4] = (bx ^ hy0 ^ hz1) & HASH_MASK;
            idx[5] = ((bx + 1) ^ hy0 ^ hz1) & HASH_MASK;
            idx[6] = (bx ^ hy1 ^ hz1) & HASH_MASK;
            idx[7] = ((bx + 1) ^ hy1 ^ hz1) & HASH_MASK;
        }

        const float w[8] = {
            wxy00 * wz0, wxy10 * wz0, wxy01 * wz0, wxy11 * wz0,
            wxy00 * wz1, wxy10 * wz1, wxy01 * wz1, wxy11 * wz1};

        f32x2 e[8];
#pragma unroll
        for (int cc = 0; cc < 8; ++cc) e[cc] = e2[idx[cc] + off];

        float f0 = 0.0f, f1 = 0.0f;
#pragma unroll
        for (int cc = 0; cc < 8; ++cc) { f0 += w[cc] * e[cc].x; f1 += w[cc] * e[cc].y; }

        acc[2 * l + 0] = f0;
        acc[2 * l + 1] = f1;
    }

    f32x4* __restrict__ o4 = reinterpret_cast<f32x4*>(out + (size_t)i * 32);
#pragma unroll
    for (int q = 0; q < 8; ++q) {
        f32x4 v;
        v.x = acc[4 * q + 0];
        v.y = acc[4 * q + 1];
        v.z = acc[4 * q + 2];
        v.w = acc[4 * q + 3];
        o4[q] = v;
    }
}

extern "C" void kernel_launch(void* const* d_in, const int* in_sizes, int n_in,
                              void* d_out, int out_size, void* d_ws, size_t ws_size,
                              hipStream_t stream) {
    const float* in = (const float*)d_in[0];
    const float* emb = (const float*)d_in[1];
    float* out = (float*)d_out;
    const int N = in_sizes[0] / 3;
    const int chunks = (N + 255) / 256;

    const size_t tab_n = (size_t)HASHED_TOTAL;          // h16x2 units, 8B-aligned base
    const size_t dtab_n = (size_t)DENSE_TOTAL + 1;      // +1 pad for alignment
    const size_t dump_n = (size_t)chunks * 13 * 256;    // h16x2 units
    const size_t ws_needed = (tab_n + dtab_n + dump_n) * sizeof(h16x2);  // ~135 MB

    if (ws_size >= ws_needed) {
        h16x2* tab = (h16x2*)d_ws;
        h16x2* dtab = tab + tab_n;
        h16x2* dump = dtab + dtab_n;
        const uint32_t total_repack = HASHED_TOTAL + DENSE_TOTAL;
        repack_kernel<<<(total_repack + 255) / 256, 256, 0, stream>>>(emb, tab, dtab);
        pass1_kernel<<<13 * chunks, 256, 0, stream>>>(in, tab, dump, N, chunks);
        pass2_kernel<<<chunks, 256, 0, stream>>>(in, dtab, dump, out, N);
    } else {
        hash_encode_fused_kernel<<<chunks, 256, 0, stream>>>(in, emb, out, N);
    }
}

// Round 8
// 917.787 us; speedup vs baseline: 1.0171x; 1.0171x over previous
//
#include <hip/hip_runtime.h>
#include <stdint.h>

#define PRIME_Y 2654435761u
#define PRIME_Z 805459861u
#define HASH_MASK 524287u   // 2^19 - 1

typedef float f32x2 __attribute__((ext_vector_type(2)));
typedef float f32x4 __attribute__((ext_vector_type(4)));

__constant__ float c_scales[16] = {
    15.f, 31.f, 63.f, 127.f, 255.f, 511.f, 1023.f, 2047.f,
    4095.f, 8191.f, 16383.f, 32767.f, 65535.f, 131071.f, 262143.f, 524287.f};
__constant__ uint32_t c_offsets[16] = {
    0u, 4913u, 40850u, 315475u, 839763u, 1364051u, 1888339u, 2412627u,
    2936915u, 3461203u, 3985491u, 4509779u, 5034067u, 5558355u, 6082643u, 6606931u};
__constant__ uint32_t c_strides[3] = {17u, 33u, 65u};

// Per-point hashed-level gather+interp, returns feature (f0,f1).
__device__ __forceinline__ f32x2 hashed_point(
    const f32x2* __restrict__ e2, uint32_t off, float scale,
    float x, float y, float z)
{
    const float posx = __fadd_rn(__fmul_rn(x, scale), 0.5f);
    const float posy = __fadd_rn(__fmul_rn(y, scale), 0.5f);
    const float posz = __fadd_rn(__fmul_rn(z, scale), 0.5f);

    const float gx = floorf(posx), gy = floorf(posy), gz = floorf(posz);
    const float fx = posx - gx, fy = posy - gy, fz = posz - gz;
    const uint32_t bx = (uint32_t)gx, by = (uint32_t)gy, bz = (uint32_t)gz;

    const float wx0 = 1.0f - fx, wx1 = fx;
    const float wy0 = 1.0f - fy, wy1 = fy;
    const float wz0 = 1.0f - fz, wz1 = fz;
    const float wxy00 = wx0 * wy0, wxy10 = wx1 * wy0;
    const float wxy01 = wx0 * wy1, wxy11 = wx1 * wy1;

    const uint32_t hy0 = by * PRIME_Y, hy1 = hy0 + PRIME_Y;
    const uint32_t hz0 = bz * PRIME_Z, hz1 = hz0 + PRIME_Z;

    uint32_t idx[8];
    idx[0] = (bx ^ hy0 ^ hz0) & HASH_MASK;
    idx[1] = ((bx + 1) ^ hy0 ^ hz0) & HASH_MASK;
    idx[2] = (bx ^ hy1 ^ hz0) & HASH_MASK;
    idx[3] = ((bx + 1) ^ hy1 ^ hz0) & HASH_MASK;
    idx[4] = (bx ^ hy0 ^ hz1) & HASH_MASK;
    idx[5] = ((bx + 1) ^ hy0 ^ hz1) & HASH_MASK;
    idx[6] = (bx ^ hy1 ^ hz1) & HASH_MASK;
    idx[7] = ((bx + 1) ^ hy1 ^ hz1) & HASH_MASK;

    const float w[8] = {
        wxy00 * wz0, wxy10 * wz0, wxy01 * wz0, wxy11 * wz0,
        wxy00 * wz1, wxy10 * wz1, wxy01 * wz1, wxy11 * wz1};

    f32x2 e[8];
#pragma unroll
    for (int c = 0; c < 8; ++c) e[c] = e2[idx[c] + off];

    float f0 = 0.0f, f1 = 0.0f;
#pragma unroll
    for (int c = 0; c < 8; ++c) {
        f0 += w[c] * e[c].x;
        f1 += w[c] * e[c].y;
    }
    f32x2 r; r.x = f0; r.y = f1;
    return r;
}

// ---- Pass 1: hashed levels 3..15, level-major, 2 points/thread;
//      dump blocked [chunk512][13][512] ----
__global__ __launch_bounds__(256) void pass1_kernel(
    const float* __restrict__ in,    // [N,3]
    const float* __restrict__ emb,   // [T,2]
    f32x2* __restrict__ dump,        // [chunks512][13][512]
    int N, int chunks)               // chunks = ceil(N/512)
{
    const int bid = blockIdx.x;
    const int lev_i = bid / chunks;                 // 0..12 -> level lev_i+3
    const int chunk = bid - lev_i * chunks;
    const int t = threadIdx.x;
    const int i0 = chunk * 512 + t;
    const int i1 = i0 + 256;
    const int level = lev_i + 3;

    const float scale = c_scales[level];
    const uint32_t off = c_offsets[level];
    const f32x2* __restrict__ e2 = reinterpret_cast<const f32x2*>(emb);
    f32x2* __restrict__ drow = dump + ((size_t)chunk * 13 + lev_i) * 512;

    if (i1 < N) {
        // both points: NT input loads (stream-once, keep table in L2)
        const float ax = __builtin_nontemporal_load(&in[3 * i0 + 0]);
        const float ay = __builtin_nontemporal_load(&in[3 * i0 + 1]);
        const float az = __builtin_nontemporal_load(&in[3 * i0 + 2]);
        const float bx_ = __builtin_nontemporal_load(&in[3 * i1 + 0]);
        const float by_ = __builtin_nontemporal_load(&in[3 * i1 + 1]);
        const float bz_ = __builtin_nontemporal_load(&in[3 * i1 + 2]);

        const f32x2 ra = hashed_point(e2, off, scale,
            (ax + 1.0f) * 0.5f, (ay + 1.0f) * 0.5f, (az + 1.0f) * 0.5f);
        const f32x2 rb = hashed_point(e2, off, scale,
            (bx_ + 1.0f) * 0.5f, (by_ + 1.0f) * 0.5f, (bz_ + 1.0f) * 0.5f);

        __builtin_nontemporal_store(ra, &drow[t]);
        __builtin_nontemporal_store(rb, &drow[t + 256]);
    } else if (i0 < N) {
        const float ax = __builtin_nontemporal_load(&in[3 * i0 + 0]);
        const float ay = __builtin_nontemporal_load(&in[3 * i0 + 1]);
        const float az = __builtin_nontemporal_load(&in[3 * i0 + 2]);
        const f32x2 ra = hashed_point(e2, off, scale,
            (ax + 1.0f) * 0.5f, (ay + 1.0f) * 0.5f, (az + 1.0f) * 0.5f);
        __builtin_nontemporal_store(ra, &drow[t]);
    }
}

// ---- Pass 2: fused dense levels 0..2 + transpose dump -> out[N][32] (PLAIN mem ops) ----
__global__ __launch_bounds__(256) void pass2_kernel(
    const float* __restrict__ in,
    const float* __restrict__ emb,
    const f32x2* __restrict__ dump,  // [chunks512][13][512]
    float* __restrict__ out, int N)
{
    const int b = blockIdx.x;
    const int t = threadIdx.x;
    const int i = b * 256 + t;
    if (i >= N) return;

    float acc[32];

    const float x = (in[3 * i + 0] + 1.0f) * 0.5f;
    const float y = (in[3 * i + 1] + 1.0f) * 0.5f;
    const float z = (in[3 * i + 2] + 1.0f) * 0.5f;

    const f32x2* __restrict__ e2 = reinterpret_cast<const f32x2*>(emb);

#pragma unroll
    for (int l = 0; l < 3; ++l) {
        const float scale = c_scales[l];
        const uint32_t off = c_offsets[l];
        const float posx = __fadd_rn(__fmul_rn(x, scale), 0.5f);
        const float posy = __fadd_rn(__fmul_rn(y, scale), 0.5f);
        const float posz = __fadd_rn(__fmul_rn(z, scale), 0.5f);
        const float gx = floorf(posx), gy = floorf(posy), gz = floorf(posz);
        const float fx = posx - gx, fy = posy - gy, fz = posz - gz;
        const uint32_t bx = (uint32_t)gx, by = (uint32_t)gy, bz = (uint32_t)gz;
        const float wx0 = 1.0f - fx, wx1 = fx;
        const float wy0 = 1.0f - fy, wy1 = fy;
        const float wz0 = 1.0f - fz, wz1 = fz;
        const float wxy00 = wx0 * wy0, wxy10 = wx1 * wy0;
        const float wxy01 = wx0 * wy1, wxy11 = wx1 * wy1;

        const uint32_t s = c_strides[l];
        const uint32_t s2 = s * s;
        const uint32_t r0 = by * s + bz * s2;
        const uint32_t r1 = r0 + s;
        const uint32_t r2 = r0 + s2;
        const uint32_t r3 = r1 + s2;
        uint32_t idx[8];
        idx[0] = bx + r0; idx[1] = bx + 1 + r0;
        idx[2] = bx + r1; idx[3] = bx + 1 + r1;
        idx[4] = bx + r2; idx[5] = bx + 1 + r2;
        idx[6] = bx + r3; idx[7] = bx + 1 + r3;

        const float w[8] = {
            wxy00 * wz0, wxy10 * wz0, wxy01 * wz0, wxy11 * wz0,
            wxy00 * wz1, wxy10 * wz1, wxy01 * wz1, wxy11 * wz1};

        f32x2 e[8];
#pragma unroll
        for (int cc = 0; cc < 8; ++cc) e[cc] = e2[idx[cc] + off];

        float f0 = 0.0f, f1 = 0.0f;
#pragma unroll
        for (int cc = 0; cc < 8; ++cc) { f0 += w[cc] * e[cc].x; f1 += w[cc] * e[cc].y; }

        acc[2 * l + 0] = f0;
        acc[2 * l + 1] = f1;
    }

    const int chunk = i >> 9;
    const int slot = i & 511;
#pragma unroll
    for (int li = 0; li < 13; ++li) {
        f32x2 f = dump[((size_t)chunk * 13 + li) * 512 + slot];
        acc[2 * (li + 3) + 0] = f.x;
        acc[2 * (li + 3) + 1] = f.y;
    }

    f32x4* __restrict__ o4 = reinterpret_cast<f32x4*>(out + (size_t)i * 32);
#pragma unroll
    for (int q = 0; q < 8; ++q) {
        f32x4 v;
        v.x = acc[4 * q + 0];
        v.y = acc[4 * q + 1];
        v.z = acc[4 * q + 2];
        v.w = acc[4 * q + 3];
        o4[q] = v;   // plain store — let L2 assemble full lines
    }
}

// ---- Fallback: fused single-pass (if ws too small) ----
__global__ __launch_bounds__(256) void hash_encode_fused_kernel(
    const float* __restrict__ in,
    const float* __restrict__ emb,
    float* __restrict__ out,
    int N)
{
    const int i = blockIdx.x * 256 + threadIdx.x;
    if (i >= N) return;

    const float x = (in[3 * i + 0] + 1.0f) * 0.5f;
    const float y = (in[3 * i + 1] + 1.0f) * 0.5f;
    const float z = (in[3 * i + 2] + 1.0f) * 0.5f;

    const f32x2* __restrict__ e2 = reinterpret_cast<const f32x2*>(emb);
    float acc[32];

#pragma unroll
    for (int l = 0; l < 16; ++l) {
        const float scale = c_scales[l];
        const uint32_t off = c_offsets[l];
        const float posx = __fadd_rn(__fmul_rn(x, scale), 0.5f);
        const float posy = __fadd_rn(__fmul_rn(y, scale), 0.5f);
        const float posz = __fadd_rn(__fmul_rn(z, scale), 0.5f);
        const float gx = floorf(posx), gy = floorf(posy), gz = floorf(posz);
        const float fx = posx - gx, fy = posy - gy, fz = posz - gz;
        const uint32_t bx = (uint32_t)gx, by = (uint32_t)gy, bz = (uint32_t)gz;
        const float wx0 = 1.0f - fx, wx1 = fx;
        const float wy0 = 1.0f - fy, wy1 = fy;
        const float wz0 = 1.0f - fz, wz1 = fz;
        const float wxy00 = wx0 * wy0, wxy10 = wx1 * wy0;
        const float wxy01 = wx0 * wy1, wxy11 = wx1 * wy1;

        uint32_t idx[8];
        if (l < 3) {
            const uint32_t s = c_strides[l];
            const uint32_t s2 = s * s;
            const uint32_t r0 = by * s + bz * s2;
            const uint32_t r1 = r0 + s;
            const uint32_t r2 = r0 + s2;
            const uint32_t r3 = r1 + s2;
            idx[0] = bx + r0; idx[1] = bx + 1 + r0;
            idx[2] = bx + r1; idx[3] = bx + 1 + r1;
            idx[4] = bx + r2; idx[5] = bx + 1 + r2;
            idx[6] = bx + r3; idx[7] = bx + 1 + r3;
        } else {
            const uint32_t hy0 = by * PRIME_Y, hy1 = hy0 + PRIME_Y;
            const uint32_t hz0 = bz * PRIME_Z, hz1 = hz0 + PRIME_Z;
            idx[0] = (bx ^ hy0 ^ hz0) & HASH_MASK;
            idx[1] = ((bx + 1) ^ hy0 ^ hz0) & HASH_MASK;
            idx[2] = (bx ^ hy1 ^ hz0) & HASH_MASK;
            idx[3] = ((bx + 1) ^ hy1 ^ hz0) & HASH_MASK;
            idx[4] = (bx ^ hy0 ^ hz1) & HASH_MASK;
            idx[5] = ((bx + 1) ^ hy0 ^ hz1) & HASH_MASK;
            idx[6] = (bx ^ hy1 ^ hz1) & HASH_MASK;
            idx[7] = ((bx + 1) ^ hy1 ^ hz1) & HASH_MASK;
        }

        const float w[8] = {
            wxy00 * wz0, wxy10 * wz0, wxy01 * wz0, wxy11 * wz0,
            wxy00 * wz1, wxy10 * wz1, wxy01 * wz1, wxy11 * wz1};

        f32x2 e[8];
#pragma unroll
        for (int cc = 0; cc < 8; ++cc) e[cc] = e2[idx[cc] + off];

        float f0 = 0.0f, f1 = 0.0f;
#pragma unroll
        for (int cc = 0; cc < 8; ++cc) { f0 += w[cc] * e[cc].x; f1 += w[cc] * e[cc].y; }

        acc[2 * l + 0] = f0;
        acc[2 * l + 1] = f1;
    }

    f32x4* __restrict__ o4 = reinterpret_cast<f32x4*>(out + (size_t)i * 32);
#pragma unroll
    for (int q = 0; q < 8; ++q) {
        f32x4 v;
        v.x = acc[4 * q + 0];
        v.y = acc[4 * q + 1];
        v.z = acc[4 * q + 2];
        v.w = acc[4 * q + 3];
        o4[q] = v;
    }
}

extern "C" void kernel_launch(void* const* d_in, const int* in_sizes, int n_in,
                              void* d_out, int out_size, void* d_ws, size_t ws_size,
                              hipStream_t stream) {
    const float* in = (const float*)d_in[0];
    const float* emb = (const float*)d_in[1];
    float* out = (float*)d_out;
    const int N = in_sizes[0] / 3;
    const int chunks512 = (N + 511) / 512;
    const int blocks256 = (N + 255) / 256;

    const size_t dump_f2 = (size_t)chunks512 * 13 * 512;         // f32x2 units
    const size_t ws_needed = dump_f2 * sizeof(f32x2);            // 208 MiB at N=2^21

    if (ws_size >= ws_needed) {
        f32x2* dump = (f32x2*)d_ws;
        pass1_kernel<<<13 * chunks512, 256, 0, stream>>>(in, emb, dump, N, chunks512);
        pass2_kernel<<<blocks256, 256, 0, stream>>>(in, emb, dump, out, N);
    } else {
        hash_encode_fused_kernel<<<blocks256, 256, 0, stream>>>(in, emb, out, N);
    }
}